// Round 5
// baseline (656.722 us; speedup 1.0000x reference)
//
#include <hip/hip_runtime.h>
#include <stdint.h>

// B=32 batch, K=1024 capsules, C=64 classes, O=32 out dim, I=32 in dim, 3 routing iters.
#define Bb 32
#define Kk 1024
#define Cc 64
#define Oo 32
#define Ii 32

typedef __attribute__((ext_vector_type(8))) short bf16x8;
typedef __attribute__((ext_vector_type(4))) float f32x4;

__device__ __forceinline__ short f2bf(float f) {
    uint32_t u = __builtin_bit_cast(uint32_t, f);
    u += 0x7fffu + ((u >> 16) & 1u);   // RNE (inputs finite)
    return (short)(u >> 16);
}
__device__ __forceinline__ float bflo(uint32_t u) { return __builtin_bit_cast(float, u << 16); }
__device__ __forceinline__ float bfhi(uint32_t u) { return __builtin_bit_cast(float, u & 0xffff0000u); }
__device__ __forceinline__ uint32_t pk2(float a, float b) {
    return (uint32_t)(uint16_t)f2bf(a) | ((uint32_t)(uint16_t)f2bf(b) << 16);
}

// uh layout (bf16 as dwords): dword = (k*64+c)*512 + half*256 + lane*4 + e.
// half0 = frag elems 0..7, half1 = elems 8..15. Elem i=t*4+r of lane (m,q):
// u_hat[b=(t&1)*16+m][o=(t>>1)*16+q*4+r]  (mfma_f32_16x16x32 C/D map).

// x transpose+convert: xT[k][b][i] bf16, dword = k*512 + b*16 + i/2.
__global__ __launch_bounds__(256) void k_xT(const float* __restrict__ x,
                                            uint32_t* __restrict__ xT) {
    const int k = blockIdx.x;
    const int tid = threadIdx.x;
    const int b = tid >> 3;
    const int i8 = (tid & 7) * 4;
    const float* xp = x + ((size_t)b * Kk + k) * Ii + i8;
    f32x4 v = *(const f32x4*)xp;
    uint32_t* dst = xT + (size_t)k * 512 + b * 16 + i8 / 2;
    dst[0] = pk2(v.x, v.y);
    dst[1] = pk2(v.z, v.w);
}

// u_hat + fused iter-0 s partials. Block = 4 waves; wave owns c = cgroup*4+wave,
// loops 16 k of its kchunk. part0[(kchunk*64+c)*64+lane][16] fp32 (raw sums; the
// 1/64 uniform-softmax weight is applied in k_redA).
__global__ __launch_bounds__(256) void k_uhat(const uint32_t* __restrict__ xT,
                                              const float* __restrict__ W,
                                              uint32_t* __restrict__ uh,
                                              float* __restrict__ part0) {
    const int kchunk = blockIdx.x & 63;
    const int cgroup = blockIdx.x >> 6;
    const int lane = threadIdx.x & 63;
    const int wave = threadIdx.x >> 6;
    const int c = cgroup * 4 + wave;
    const int m = lane & 15;
    const int q = lane >> 4;

    float acc[16];
#pragma unroll
    for (int i = 0; i < 16; ++i) acc[i] = 0.f;

    for (int kl = 0; kl < 16; ++kl) {
        const int k = kchunk * 16 + kl;
        // B frags: xT[k][nb*16+m][q*8..+8) -> 16 B/lane, coalesced, pre-bf16
        const uint32_t* xp = xT + (size_t)k * 512 + m * 16 + q * 4;
        bf16x8 b0 = *(const bf16x8*)xp;
        bf16x8 b1 = *(const bf16x8*)(xp + 256);
        // A frags: W[k][c][mo*16+m][q*8..+8) fp32, nontemporal (read-once)
        bf16x8 a0, a1;
        {
            const float* wp = W + (size_t)((k * Cc + c) * Oo + m) * Ii + q * 8;
            f32x4 u0 = __builtin_nontemporal_load((const f32x4*)wp);
            f32x4 u1 = __builtin_nontemporal_load((const f32x4*)(wp + 4));
            f32x4 u2 = __builtin_nontemporal_load((const f32x4*)(wp + 512));
            f32x4 u3 = __builtin_nontemporal_load((const f32x4*)(wp + 516));
            bf16x8 t;
            t[0] = f2bf(u0.x); t[1] = f2bf(u0.y); t[2] = f2bf(u0.z); t[3] = f2bf(u0.w);
            t[4] = f2bf(u1.x); t[5] = f2bf(u1.y); t[6] = f2bf(u1.z); t[7] = f2bf(u1.w);
            a0 = t;
            t[0] = f2bf(u2.x); t[1] = f2bf(u2.y); t[2] = f2bf(u2.z); t[3] = f2bf(u2.w);
            t[4] = f2bf(u3.x); t[5] = f2bf(u3.y); t[6] = f2bf(u3.z); t[7] = f2bf(u3.w);
            a1 = t;
        }
        const f32x4 z = {0.f, 0.f, 0.f, 0.f};
        f32x4 d0 = __builtin_amdgcn_mfma_f32_16x16x32_bf16(a0, b0, z, 0, 0, 0);
        f32x4 d1 = __builtin_amdgcn_mfma_f32_16x16x32_bf16(a0, b1, z, 0, 0, 0);
        f32x4 d2 = __builtin_amdgcn_mfma_f32_16x16x32_bf16(a1, b0, z, 0, 0, 0);
        f32x4 d3 = __builtin_amdgcn_mfma_f32_16x16x32_bf16(a1, b1, z, 0, 0, 0);

        uint4 p0, p1;
        p0.x = pk2(d0.x, d0.y); p0.y = pk2(d0.z, d0.w);
        p0.z = pk2(d1.x, d1.y); p0.w = pk2(d1.z, d1.w);
        p1.x = pk2(d2.x, d2.y); p1.y = pk2(d2.z, d2.w);
        p1.z = pk2(d3.x, d3.y); p1.w = pk2(d3.z, d3.w);
        uint32_t* dst = uh + (size_t)(k * Cc + c) * 512 + lane * 4;
        *(uint4*)dst = p0;
        *(uint4*)(dst + 256) = p1;

        acc[0]  += d0.x; acc[1]  += d0.y; acc[2]  += d0.z; acc[3]  += d0.w;
        acc[4]  += d1.x; acc[5]  += d1.y; acc[6]  += d1.z; acc[7]  += d1.w;
        acc[8]  += d2.x; acc[9]  += d2.y; acc[10] += d2.z; acc[11] += d2.w;
        acc[12] += d3.x; acc[13] += d3.y; acc[14] += d3.z; acc[15] += d3.w;
    }
#pragma unroll
    for (int t = 0; t < 4; ++t) {
        f32x4 v = {acc[t * 4 + 0], acc[t * 4 + 1], acc[t * 4 + 2], acc[t * 4 + 3]};
        *(f32x4*)&part0[(((size_t)(kchunk * Cc + c)) * 64 + lane) * 16 + t * 4] = v;
    }
}

// Reduce 64 fp32 kchunk-partials, scale by 1/64, squash -> vfrag[c][lane][16].
__global__ __launch_bounds__(256) void k_redA(const float* __restrict__ part0,
                                              float* __restrict__ vfrag) {
    __shared__ float red[4 * 64 * 17];
    const int c = blockIdx.x;
    const int tid = threadIdx.x;
    const int lane = tid & 63;
    const int grp = tid >> 6;

    float acc[16];
#pragma unroll
    for (int i = 0; i < 16; ++i) acc[i] = 0.f;
    for (int ch = grp * 16; ch < grp * 16 + 16; ++ch) {
        const float* p = part0 + (((size_t)(ch * Cc + c)) * 64 + lane) * 16;
#pragma unroll
        for (int t = 0; t < 4; ++t) {
            f32x4 v = *(const f32x4*)(p + t * 4);
            acc[t * 4 + 0] += v.x; acc[t * 4 + 1] += v.y;
            acc[t * 4 + 2] += v.z; acc[t * 4 + 3] += v.w;
        }
    }
#pragma unroll
    for (int i = 0; i < 16; ++i) red[(grp * 64 + lane) * 17 + i] = acc[i];
    __syncthreads();

    if (tid < 64) {
        float a[16];
#pragma unroll
        for (int i = 0; i < 16; ++i)
            a[i] = (red[tid * 17 + i] + red[(64 + tid) * 17 + i]
                  + red[(128 + tid) * 17 + i] + red[(192 + tid) * 17 + i]) * (1.f / 64.f);
        float sq0 = 0.f, sq1 = 0.f;
#pragma unroll
        for (int r = 0; r < 4; ++r) {
            sq0 += a[r] * a[r] + a[8 + r] * a[8 + r];
            sq1 += a[4 + r] * a[4 + r] + a[12 + r] * a[12 + r];
        }
        sq0 += __shfl_xor(sq0, 16); sq0 += __shfl_xor(sq0, 32);
        sq1 += __shfl_xor(sq1, 16); sq1 += __shfl_xor(sq1, 32);
        const float c0 = sq0 / ((1.f + sq0) * sqrtf(sq0 + 1e-8f));
        const float c1 = sq1 / ((1.f + sq1) * sqrtf(sq1 + 1e-8f));
#pragma unroll
        for (int r = 0; r < 4; ++r) {
            a[r] *= c0; a[8 + r] *= c0;
            a[4 + r] *= c1; a[12 + r] *= c1;
        }
        float* vp = vfrag + ((size_t)c * 64 + tid) * 16;
#pragma unroll
        for (int t = 0; t < 4; ++t) {
            f32x4 v = {a[t * 4 + 0], a[t * 4 + 1], a[t * 4 + 2], a[t * 4 + 3]};
            *(f32x4*)(vp + t * 4) = v;
        }
    }
}

// Fused routing iteration, uh read ONCE per k (register retention across the
// softmax barriers). R4 geometry (1024 thr, 16 waves, 4 c/wave) makes this
// affordable: uh regs = 4c x 32B = 32 VGPR; peak ~ acc 64 + uh 32 + vfrag 16
// + temps < 128 cap -> 16 waves/CU kept (unlike R2/R3 retention attempts).
// Per kl: load uh -> agreement -> bar -> softmax(kl) -> bar -> s-accum (same
// regs). agr double-buffered so 2 barriers/kl suffice (WAR is 2 barriers away).
template <bool FINAL>
__global__ __launch_bounds__(1024) void k_iter(const uint32_t* __restrict__ uh,
                                               const float* __restrict__ vfrag,
                                               float* __restrict__ bbuf,    // [k][b][c]
                                               uint32_t* __restrict__ partB,
                                               float* __restrict__ outc) {  // [b][k][c]
    __shared__ float agr[2][64 * 33];   // [buf][c][32 b + pad]
    const int tid = threadIdx.x;
    const int lane = tid & 63;
    const int w = tid >> 6;       // 0..15
    const int m = lane & 15;
    const int q = lane >> 4;
    const int k0 = blockIdx.x * 4;

    float acc[4][16];
#pragma unroll
    for (int cg = 0; cg < 4; ++cg)
#pragma unroll
        for (int i = 0; i < 16; ++i) acc[cg][i] = 0.f;

#pragma unroll 1
    for (int kl = 0; kl < 4; ++kl) {
        const int k = k0 + kl;
        float* ag = agr[kl & 1];

        // single uh read for this k: 4 c x 32 B/thread, retained in regs
        uint4 r0[4], r1[4];
#pragma unroll
        for (int cc = 0; cc < 4; ++cc) {
            const uint32_t* up = uh + (size_t)(k * Cc + w * 4 + cc) * 512 + lane * 4;
            r0[cc] = *(const uint4*)up;
            r1[cc] = *(const uint4*)(up + 256);
        }

        // phase 1: agreement. wave w owns c = w*4 .. w*4+3
#pragma unroll
        for (int cc = 0; cc < 4; ++cc) {
            const int c = w * 4 + cc;
            const float* vp = vfrag + ((size_t)c * 64 + lane) * 16;
            f32x4 vv0 = *(const f32x4*)(vp);
            f32x4 vv1 = *(const f32x4*)(vp + 4);
            f32x4 vv2 = *(const f32x4*)(vp + 8);
            f32x4 vv3 = *(const f32x4*)(vp + 12);
            const uint4 q0 = r0[cc];
            const uint4 q1 = r1[cc];
            float p0 = bflo(q0.x) * vv0.x + bfhi(q0.x) * vv0.y
                     + bflo(q0.y) * vv0.z + bfhi(q0.y) * vv0.w
                     + bflo(q1.x) * vv2.x + bfhi(q1.x) * vv2.y
                     + bflo(q1.y) * vv2.z + bfhi(q1.y) * vv2.w;
            float p1 = bflo(q0.z) * vv1.x + bfhi(q0.z) * vv1.y
                     + bflo(q0.w) * vv1.z + bfhi(q0.w) * vv1.w
                     + bflo(q1.z) * vv3.x + bfhi(q1.z) * vv3.y
                     + bflo(q1.w) * vv3.z + bfhi(q1.w) * vv3.w;
            p0 += __shfl_xor(p0, 16);
            p0 += __shfl_xor(p0, 32);
            p1 += __shfl_xor(p1, 16);
            p1 += __shfl_xor(p1, 32);
            if (q == 0) {
                ag[c * 33 + m] = p0;
                ag[c * 33 + 16 + m] = p1;
            }
        }
        __syncthreads();

        // phase 2: softmax over c for this kl: 128 threads, quad per b-row, 16 c each
        if (tid < 128) {
            const int sub = tid & 3;
            const int b = tid >> 2;        // 0..31
            const int cbase = sub * 16;
            float r[16];
#pragma unroll
            for (int j = 0; j < 16; ++j) r[j] = ag[(cbase + j) * 33 + b];
            if (!FINAL) {
                float* bp = bbuf + (size_t)(k * Bb + b) * Cc + cbase;
#pragma unroll
                for (int j = 0; j < 16; ++j) bp[j] = r[j];
            } else {
                const float* bp = bbuf + (size_t)(k * Bb + b) * Cc + cbase;
#pragma unroll
                for (int j = 0; j < 16; ++j) r[j] += bp[j];
            }
            float mx = r[0];
#pragma unroll
            for (int j = 1; j < 16; ++j) mx = fmaxf(mx, r[j]);
            mx = fmaxf(mx, __shfl_xor(mx, 1));
            mx = fmaxf(mx, __shfl_xor(mx, 2));
            float sum = 0.f;
#pragma unroll
            for (int j = 0; j < 16; ++j) { r[j] = __expf(r[j] - mx); sum += r[j]; }
            sum += __shfl_xor(sum, 1);
            sum += __shfl_xor(sum, 2);
            const float inv = 1.f / sum;
#pragma unroll
            for (int j = 0; j < 16; ++j) r[j] *= inv;
            if (FINAL) {
                float* op = outc + (size_t)(b * Kk + k) * Cc + cbase;
#pragma unroll
                for (int j = 0; j < 16; ++j) op[j] = r[j];
            }
#pragma unroll
            for (int j = 0; j < 16; ++j) ag[(cbase + j) * 33 + b] = r[j];
        }
        __syncthreads();

        // phase 3: s-accum for this kl, reusing the SAME uh registers
#pragma unroll
        for (int cc = 0; cc < 4; ++cc) {
            const int c = w * 4 + cc;
            const uint4 q0 = r0[cc];
            const uint4 q1 = r1[cc];
            const float w0 = ag[c * 33 + m];
            const float w1 = ag[c * 33 + 16 + m];
            acc[cc][0]  += w0 * bflo(q0.x);  acc[cc][1]  += w0 * bfhi(q0.x);
            acc[cc][2]  += w0 * bflo(q0.y);  acc[cc][3]  += w0 * bfhi(q0.y);
            acc[cc][4]  += w1 * bflo(q0.z);  acc[cc][5]  += w1 * bfhi(q0.z);
            acc[cc][6]  += w1 * bflo(q0.w);  acc[cc][7]  += w1 * bfhi(q0.w);
            acc[cc][8]  += w0 * bflo(q1.x);  acc[cc][9]  += w0 * bfhi(q1.x);
            acc[cc][10] += w0 * bflo(q1.y);  acc[cc][11] += w0 * bfhi(q1.y);
            acc[cc][12] += w1 * bflo(q1.z);  acc[cc][13] += w1 * bfhi(q1.z);
            acc[cc][14] += w1 * bflo(q1.w);  acc[cc][15] += w1 * bfhi(q1.w);
        }
    }

    // epilogue: pack + write partB (bf16)
    const int chunk = blockIdx.x;
#pragma unroll
    for (int cg = 0; cg < 4; ++cg) {
        const int c = w * 4 + cg;
        uint4 o0, o1;
        o0.x = pk2(acc[cg][0],  acc[cg][1]);  o0.y = pk2(acc[cg][2],  acc[cg][3]);
        o0.z = pk2(acc[cg][4],  acc[cg][5]);  o0.w = pk2(acc[cg][6],  acc[cg][7]);
        o1.x = pk2(acc[cg][8],  acc[cg][9]);  o1.y = pk2(acc[cg][10], acc[cg][11]);
        o1.z = pk2(acc[cg][12], acc[cg][13]); o1.w = pk2(acc[cg][14], acc[cg][15]);
        uint32_t* dst = partB + ((size_t)(c * 256 + chunk) * 64 + lane) * 8;
        *(uint4*)dst = o0;
        *(uint4*)(dst + 4) = o1;
    }
}

// Stage-1 reduce of 256 bf16 chunk-partials: block = (c, g of 8), sums 32 chunks.
__global__ __launch_bounds__(256) void k_red1(const uint32_t* __restrict__ partB,
                                              float* __restrict__ part2) {
    __shared__ float red[4 * 64 * 17];
    const int cb = blockIdx.x;          // c*8+g
    const int c = cb >> 3;
    const int g = cb & 7;
    const int tid = threadIdx.x;
    const int lane = tid & 63;
    const int ww = tid >> 6;

    float acc[16];
#pragma unroll
    for (int i = 0; i < 16; ++i) acc[i] = 0.f;
    for (int ch = g * 32 + ww * 8; ch < g * 32 + ww * 8 + 8; ++ch) {
        const uint32_t* p = partB + ((size_t)(c * 256 + ch) * 64 + lane) * 8;
        uint4 a = *(const uint4*)p;
        uint4 b = *(const uint4*)(p + 4);
        acc[0]  += bflo(a.x);  acc[1]  += bfhi(a.x);
        acc[2]  += bflo(a.y);  acc[3]  += bfhi(a.y);
        acc[4]  += bflo(a.z);  acc[5]  += bfhi(a.z);
        acc[6]  += bflo(a.w);  acc[7]  += bfhi(a.w);
        acc[8]  += bflo(b.x);  acc[9]  += bfhi(b.x);
        acc[10] += bflo(b.y);  acc[11] += bfhi(b.y);
        acc[12] += bflo(b.z);  acc[13] += bfhi(b.z);
        acc[14] += bflo(b.w);  acc[15] += bfhi(b.w);
    }
#pragma unroll
    for (int i = 0; i < 16; ++i) red[(ww * 64 + lane) * 17 + i] = acc[i];
    __syncthreads();

    if (tid < 64) {
        float a[16];
#pragma unroll
        for (int i = 0; i < 16; ++i)
            a[i] = red[tid * 17 + i] + red[(64 + tid) * 17 + i]
                 + red[(128 + tid) * 17 + i] + red[(192 + tid) * 17 + i];
        float* dst = part2 + ((size_t)cb * 64 + tid) * 16;
#pragma unroll
        for (int t = 0; t < 4; ++t) {
            f32x4 v = {a[t * 4 + 0], a[t * 4 + 1], a[t * 4 + 2], a[t * 4 + 3]};
            *(f32x4*)(dst + t * 4) = v;
        }
    }
}

// Stage-2: sum 8 fp32 partials + squash -> vfrag (+ out_v on FINAL).
template <bool FINAL>
__global__ __launch_bounds__(64) void k_red2(const float* __restrict__ part2,
                                             float* __restrict__ vfrag,
                                             float* __restrict__ out_v) {
    const int c = blockIdx.x;
    const int lane = threadIdx.x;
    const int m = lane & 15;
    const int q = lane >> 4;

    float a[16];
#pragma unroll
    for (int i = 0; i < 16; ++i) a[i] = 0.f;
    for (int g = 0; g < 8; ++g) {
        const float* p = part2 + ((size_t)(c * 8 + g) * 64 + lane) * 16;
#pragma unroll
        for (int t = 0; t < 4; ++t) {
            f32x4 v = *(const f32x4*)(p + t * 4);
            a[t * 4 + 0] += v.x; a[t * 4 + 1] += v.y;
            a[t * 4 + 2] += v.z; a[t * 4 + 3] += v.w;
        }
    }
    float sq0 = 0.f, sq1 = 0.f;
#pragma unroll
    for (int r = 0; r < 4; ++r) {
        sq0 += a[r] * a[r] + a[8 + r] * a[8 + r];
        sq1 += a[4 + r] * a[4 + r] + a[12 + r] * a[12 + r];
    }
    sq0 += __shfl_xor(sq0, 16); sq0 += __shfl_xor(sq0, 32);
    sq1 += __shfl_xor(sq1, 16); sq1 += __shfl_xor(sq1, 32);
    const float c0 = sq0 / ((1.f + sq0) * sqrtf(sq0 + 1e-8f));
    const float c1 = sq1 / ((1.f + sq1) * sqrtf(sq1 + 1e-8f));
#pragma unroll
    for (int r = 0; r < 4; ++r) {
        a[r] *= c0; a[8 + r] *= c0;
        a[4 + r] *= c1; a[12 + r] *= c1;
    }
    float* vp = vfrag + ((size_t)c * 64 + lane) * 16;
#pragma unroll
    for (int t = 0; t < 4; ++t) {
        f32x4 v = {a[t * 4 + 0], a[t * 4 + 1], a[t * 4 + 2], a[t * 4 + 3]};
        *(f32x4*)(vp + t * 4) = v;
    }
    if (FINAL) {
#pragma unroll
        for (int t = 0; t < 4; ++t)
#pragma unroll
            for (int r = 0; r < 4; ++r) {
                const int b = (t & 1) * 16 + m;
                const int o = (t >> 1) * 16 + q * 4 + r;
                out_v[((size_t)b * Cc + c) * Oo + o] = a[t * 4 + r];
            }
    }
}

extern "C" void kernel_launch(void* const* d_in, const int* in_sizes, int n_in,
                              void* d_out, int out_size, void* d_ws, size_t ws_size,
                              hipStream_t stream) {
    (void)in_sizes; (void)n_in; (void)out_size;
    const float* x = (const float*)d_in[0];
    const float* W = (const float*)d_in[1];
    float* out_v = (float*)d_out;                  // [B][C][O]
    float* out_c = out_v + Bb * Cc * Oo;           // [B][K][C]

    char* ws = (char*)d_ws;
    const size_t UH_BYTES = (size_t)Kk * Cc * 512 * 4;            // 128 MiB (bf16)
    const size_t XT_BYTES = (size_t)Kk * 512 * 4;                 // 2 MiB
    const size_t P0_BYTES = (size_t)64 * Cc * 64 * 16 * 4;        // 16 MiB
    const size_t PB_BYTES = (size_t)Cc * 256 * 64 * 8 * 4;        // 32 MiB
    const size_t P2_BYTES = (size_t)512 * 64 * 16 * 4;            // 2 MiB
    const size_t BB_BYTES = (size_t)Kk * Bb * Cc * 4;             // 8 MiB
    const size_t VF_BYTES = (size_t)Cc * 64 * 16 * 4;             // 256 KiB

    uint32_t* uh = (uint32_t*)ws;                      ws += UH_BYTES;
    uint32_t* xT = (uint32_t*)ws;                      ws += XT_BYTES;
    float* part0  = (float*)ws;                        ws += P0_BYTES;
    uint32_t* partB = (uint32_t*)ws;                   ws += PB_BYTES;
    float* part2  = (float*)ws;                        ws += P2_BYTES;
    float* bbuf   = (float*)ws;                        ws += BB_BYTES;
    float* vfrag  = (float*)ws;                        ws += VF_BYTES;
    const size_t NEED = UH_BYTES + XT_BYTES + P0_BYTES + PB_BYTES + P2_BYTES + BB_BYTES + VF_BYTES;
    if (ws_size < NEED) return;

    k_xT<<<Kk, 256, 0, stream>>>(x, xT);
    // u_hat + fused iter-0 s partials
    k_uhat<<<1024, 256, 0, stream>>>(xT, W, uh, part0);
    k_redA<<<Cc, 256, 0, stream>>>(part0, vfrag);            // v0
    // iter 1: agreement(v0) -> b1 -> softmax c1 -> s1 partials
    k_iter<false><<<256, 1024, 0, stream>>>(uh, vfrag, bbuf, partB, nullptr);
    k_red1<<<512, 256, 0, stream>>>(partB, part2);
    k_red2<false><<<Cc, 64, 0, stream>>>(part2, vfrag, nullptr);   // v1
    // iter 2: agreement(v1) -> b2 -> softmax c2 (out_c) -> s2 partials
    k_iter<true><<<256, 1024, 0, stream>>>(uh, vfrag, bbuf, partB, out_c);
    k_red1<<<512, 256, 0, stream>>>(partB, part2);
    k_red2<true><<<Cc, 64, 0, stream>>>(part2, vfrag, out_v);      // v2 = out_v
}

// Round 6
// 481.617 us; speedup vs baseline: 1.3636x; 1.3636x over previous
//
#include <hip/hip_runtime.h>
#include <stdint.h>

// B=32 batch, K=1024 capsules, C=64 classes, O=32 out dim, I=32 in dim, 3 routing iters.
#define Bb 32
#define Kk 1024
#define Cc 64
#define Oo 32
#define Ii 32

typedef __attribute__((ext_vector_type(8))) short bf16x8;
typedef __attribute__((ext_vector_type(4))) float f32x4;

__device__ __forceinline__ short f2bf(float f) {
    uint32_t u = __builtin_bit_cast(uint32_t, f);
    u += 0x7fffu + ((u >> 16) & 1u);   // RNE (inputs finite)
    return (short)(u >> 16);
}
__device__ __forceinline__ float bflo(uint32_t u) { return __builtin_bit_cast(float, u << 16); }
__device__ __forceinline__ float bfhi(uint32_t u) { return __builtin_bit_cast(float, u & 0xffff0000u); }
__device__ __forceinline__ uint32_t pk2(float a, float b) {
    return (uint32_t)(uint16_t)f2bf(a) | ((uint32_t)(uint16_t)f2bf(b) << 16);
}

// uh layout (bf16 as dwords): dword = (k*64+c)*512 + half*256 + lane*4 + e.
// half0 = frag elems 0..7, half1 = elems 8..15. Elem i=t*4+r of lane (m,q):
// u_hat[b=(t&1)*16+m][o=(t>>1)*16+q*4+r]  (mfma_f32_16x16x32 C/D map).

// x transpose+convert: xT[k][b][i] bf16, dword = k*512 + b*16 + i/2.
__global__ __launch_bounds__(256) void k_xT(const float* __restrict__ x,
                                            uint32_t* __restrict__ xT) {
    const int k = blockIdx.x;
    const int tid = threadIdx.x;
    const int b = tid >> 3;
    const int i8 = (tid & 7) * 4;
    const float* xp = x + ((size_t)b * Kk + k) * Ii + i8;
    f32x4 v = *(const f32x4*)xp;
    uint32_t* dst = xT + (size_t)k * 512 + b * 16 + i8 / 2;
    dst[0] = pk2(v.x, v.y);
    dst[1] = pk2(v.z, v.w);
}

// u_hat + fused iter-0 s partials. Block = 4 waves; wave owns c = cgroup*4+wave,
// loops 16 k of its kchunk. part0[(kchunk*64+c)*64+lane][16] fp32 (raw sums; the
// 1/64 uniform-softmax weight is applied in k_redA).
__global__ __launch_bounds__(256) void k_uhat(const uint32_t* __restrict__ xT,
                                              const float* __restrict__ W,
                                              uint32_t* __restrict__ uh,
                                              float* __restrict__ part0) {
    const int kchunk = blockIdx.x & 63;
    const int cgroup = blockIdx.x >> 6;
    const int lane = threadIdx.x & 63;
    const int wave = threadIdx.x >> 6;
    const int c = cgroup * 4 + wave;
    const int m = lane & 15;
    const int q = lane >> 4;

    float acc[16];
#pragma unroll
    for (int i = 0; i < 16; ++i) acc[i] = 0.f;

    for (int kl = 0; kl < 16; ++kl) {
        const int k = kchunk * 16 + kl;
        // B frags: xT[k][nb*16+m][q*8..+8) -> 16 B/lane, coalesced, pre-bf16
        const uint32_t* xp = xT + (size_t)k * 512 + m * 16 + q * 4;
        bf16x8 b0 = *(const bf16x8*)xp;
        bf16x8 b1 = *(const bf16x8*)(xp + 256);
        // A frags: W[k][c][mo*16+m][q*8..+8) fp32, nontemporal (read-once)
        bf16x8 a0, a1;
        {
            const float* wp = W + (size_t)((k * Cc + c) * Oo + m) * Ii + q * 8;
            f32x4 u0 = __builtin_nontemporal_load((const f32x4*)wp);
            f32x4 u1 = __builtin_nontemporal_load((const f32x4*)(wp + 4));
            f32x4 u2 = __builtin_nontemporal_load((const f32x4*)(wp + 512));
            f32x4 u3 = __builtin_nontemporal_load((const f32x4*)(wp + 516));
            bf16x8 t;
            t[0] = f2bf(u0.x); t[1] = f2bf(u0.y); t[2] = f2bf(u0.z); t[3] = f2bf(u0.w);
            t[4] = f2bf(u1.x); t[5] = f2bf(u1.y); t[6] = f2bf(u1.z); t[7] = f2bf(u1.w);
            a0 = t;
            t[0] = f2bf(u2.x); t[1] = f2bf(u2.y); t[2] = f2bf(u2.z); t[3] = f2bf(u2.w);
            t[4] = f2bf(u3.x); t[5] = f2bf(u3.y); t[6] = f2bf(u3.z); t[7] = f2bf(u3.w);
            a1 = t;
        }
        const f32x4 z = {0.f, 0.f, 0.f, 0.f};
        f32x4 d0 = __builtin_amdgcn_mfma_f32_16x16x32_bf16(a0, b0, z, 0, 0, 0);
        f32x4 d1 = __builtin_amdgcn_mfma_f32_16x16x32_bf16(a0, b1, z, 0, 0, 0);
        f32x4 d2 = __builtin_amdgcn_mfma_f32_16x16x32_bf16(a1, b0, z, 0, 0, 0);
        f32x4 d3 = __builtin_amdgcn_mfma_f32_16x16x32_bf16(a1, b1, z, 0, 0, 0);

        uint4 p0, p1;
        p0.x = pk2(d0.x, d0.y); p0.y = pk2(d0.z, d0.w);
        p0.z = pk2(d1.x, d1.y); p0.w = pk2(d1.z, d1.w);
        p1.x = pk2(d2.x, d2.y); p1.y = pk2(d2.z, d2.w);
        p1.z = pk2(d3.x, d3.y); p1.w = pk2(d3.z, d3.w);
        uint32_t* dst = uh + (size_t)(k * Cc + c) * 512 + lane * 4;
        *(uint4*)dst = p0;
        *(uint4*)(dst + 256) = p1;

        acc[0]  += d0.x; acc[1]  += d0.y; acc[2]  += d0.z; acc[3]  += d0.w;
        acc[4]  += d1.x; acc[5]  += d1.y; acc[6]  += d1.z; acc[7]  += d1.w;
        acc[8]  += d2.x; acc[9]  += d2.y; acc[10] += d2.z; acc[11] += d2.w;
        acc[12] += d3.x; acc[13] += d3.y; acc[14] += d3.z; acc[15] += d3.w;
    }
#pragma unroll
    for (int t = 0; t < 4; ++t) {
        f32x4 v = {acc[t * 4 + 0], acc[t * 4 + 1], acc[t * 4 + 2], acc[t * 4 + 3]};
        *(f32x4*)&part0[(((size_t)(kchunk * Cc + c)) * 64 + lane) * 16 + t * 4] = v;
    }
}

// Reduce 64 fp32 kchunk-partials, scale by 1/64, squash -> vfrag[c][lane][16].
__global__ __launch_bounds__(256) void k_redA(const float* __restrict__ part0,
                                              float* __restrict__ vfrag) {
    __shared__ float red[4 * 64 * 17];
    const int c = blockIdx.x;
    const int tid = threadIdx.x;
    const int lane = tid & 63;
    const int grp = tid >> 6;

    float acc[16];
#pragma unroll
    for (int i = 0; i < 16; ++i) acc[i] = 0.f;
    for (int ch = grp * 16; ch < grp * 16 + 16; ++ch) {
        const float* p = part0 + (((size_t)(ch * Cc + c)) * 64 + lane) * 16;
#pragma unroll
        for (int t = 0; t < 4; ++t) {
            f32x4 v = *(const f32x4*)(p + t * 4);
            acc[t * 4 + 0] += v.x; acc[t * 4 + 1] += v.y;
            acc[t * 4 + 2] += v.z; acc[t * 4 + 3] += v.w;
        }
    }
#pragma unroll
    for (int i = 0; i < 16; ++i) red[(grp * 64 + lane) * 17 + i] = acc[i];
    __syncthreads();

    if (tid < 64) {
        float a[16];
#pragma unroll
        for (int i = 0; i < 16; ++i)
            a[i] = (red[tid * 17 + i] + red[(64 + tid) * 17 + i]
                  + red[(128 + tid) * 17 + i] + red[(192 + tid) * 17 + i]) * (1.f / 64.f);
        float sq0 = 0.f, sq1 = 0.f;
#pragma unroll
        for (int r = 0; r < 4; ++r) {
            sq0 += a[r] * a[r] + a[8 + r] * a[8 + r];
            sq1 += a[4 + r] * a[4 + r] + a[12 + r] * a[12 + r];
        }
        sq0 += __shfl_xor(sq0, 16); sq0 += __shfl_xor(sq0, 32);
        sq1 += __shfl_xor(sq1, 16); sq1 += __shfl_xor(sq1, 32);
        const float c0 = sq0 / ((1.f + sq0) * sqrtf(sq0 + 1e-8f));
        const float c1 = sq1 / ((1.f + sq1) * sqrtf(sq1 + 1e-8f));
#pragma unroll
        for (int r = 0; r < 4; ++r) {
            a[r] *= c0; a[8 + r] *= c0;
            a[4 + r] *= c1; a[12 + r] *= c1;
        }
        float* vp = vfrag + ((size_t)c * 64 + tid) * 16;
#pragma unroll
        for (int t = 0; t < 4; ++t) {
            f32x4 v = {a[t * 4 + 0], a[t * 4 + 1], a[t * 4 + 2], a[t * 4 + 3]};
            *(f32x4*)(vp + t * 4) = v;
        }
    }
}

// Fused routing iteration: agreement(v) -> b update -> softmax(c_ij in LDS)
// -> s-partial accumulation. Double-read of uh (proven cheaper than holding it:
// R2/R3/R5 all showed retention costs occupancy/MLP more than the L3 re-read).
// Block = 1024 threads (16 waves), wave owns 4 c -> acc = 64 VGPR, acc init
// deferred to after agreement -> peak < 128 cap -> 16 waves/CU.
// Block: 4 k, all 64 c. Grid 256 = 1 block/CU.
template <bool FINAL>
__global__ __launch_bounds__(1024) void k_iter(const uint32_t* __restrict__ uh,
                                               const float* __restrict__ vfrag,
                                               float* __restrict__ bbuf,    // [k][b][c]
                                               uint32_t* __restrict__ partB,
                                               float* __restrict__ outc) {  // [b][k][c]
    __shared__ float agr[4 * 64 * 33];   // [kl][c][32 b + pad]
    const int tid = threadIdx.x;
    const int lane = tid & 63;
    const int w = tid >> 6;       // 0..15
    const int m = lane & 15;
    const int q = lane >> 4;
    const int k0 = blockIdx.x * 4;

    // phase 1: agreement. wave w owns c = w*4 .. w*4+3
#pragma unroll
    for (int cc = 0; cc < 4; ++cc) {
        const int c = w * 4 + cc;
        const float* vp = vfrag + ((size_t)c * 64 + lane) * 16;
        f32x4 vv0 = *(const f32x4*)(vp);
        f32x4 vv1 = *(const f32x4*)(vp + 4);
        f32x4 vv2 = *(const f32x4*)(vp + 8);
        f32x4 vv3 = *(const f32x4*)(vp + 12);
#pragma unroll
        for (int kl = 0; kl < 4; ++kl) {
            const uint32_t* up = uh + (size_t)((k0 + kl) * Cc + c) * 512 + lane * 4;
            uint4 q0 = *(const uint4*)up;
            uint4 q1 = *(const uint4*)(up + 256);
            float p0 = bflo(q0.x) * vv0.x + bfhi(q0.x) * vv0.y
                     + bflo(q0.y) * vv0.z + bfhi(q0.y) * vv0.w
                     + bflo(q1.x) * vv2.x + bfhi(q1.x) * vv2.y
                     + bflo(q1.y) * vv2.z + bfhi(q1.y) * vv2.w;
            float p1 = bflo(q0.z) * vv1.x + bfhi(q0.z) * vv1.y
                     + bflo(q0.w) * vv1.z + bfhi(q0.w) * vv1.w
                     + bflo(q1.z) * vv3.x + bfhi(q1.z) * vv3.y
                     + bflo(q1.w) * vv3.z + bfhi(q1.w) * vv3.w;
            p0 += __shfl_xor(p0, 16);
            p0 += __shfl_xor(p0, 32);
            p1 += __shfl_xor(p1, 16);
            p1 += __shfl_xor(p1, 32);
            if (q == 0) {
                agr[(kl * 64 + c) * 33 + m] = p0;
                agr[(kl * 64 + c) * 33 + 16 + m] = p1;
            }
        }
    }
    __syncthreads();

    // phase 2: softmax over c: 512 threads, quad (shfl 1,2) per (kl,b) row, 16 c each
    if (tid < 512) {
        const int sub = tid & 3;
        const int row = tid >> 2;      // 0..127
        const int kl = row >> 5;
        const int b = row & 31;
        const int k = k0 + kl;
        const int cbase = sub * 16;
        float r[16];
#pragma unroll
        for (int j = 0; j < 16; ++j) r[j] = agr[(kl * 64 + cbase + j) * 33 + b];
        if (!FINAL) {
            float* bp = bbuf + (size_t)(k * Bb + b) * Cc + cbase;
#pragma unroll
            for (int j = 0; j < 16; ++j) bp[j] = r[j];
        } else {
            const float* bp = bbuf + (size_t)(k * Bb + b) * Cc + cbase;
#pragma unroll
            for (int j = 0; j < 16; ++j) r[j] += bp[j];
        }
        float mx = r[0];
#pragma unroll
        for (int j = 1; j < 16; ++j) mx = fmaxf(mx, r[j]);
        mx = fmaxf(mx, __shfl_xor(mx, 1));
        mx = fmaxf(mx, __shfl_xor(mx, 2));
        float sum = 0.f;
#pragma unroll
        for (int j = 0; j < 16; ++j) { r[j] = __expf(r[j] - mx); sum += r[j]; }
        sum += __shfl_xor(sum, 1);
        sum += __shfl_xor(sum, 2);
        const float inv = 1.f / sum;
#pragma unroll
        for (int j = 0; j < 16; ++j) r[j] *= inv;
        if (FINAL) {
            float* op = outc + (size_t)(b * Kk + k) * Cc + cbase;
#pragma unroll
            for (int j = 0; j < 16; ++j) op[j] = r[j];
        }
#pragma unroll
        for (int j = 0; j < 16; ++j) agr[(kl * 64 + cbase + j) * 33 + b] = r[j];
    }
    __syncthreads();

    // phase 3: s-accum (acc initialized here, after agreement, to keep reg peak low)
    float acc[4][16];
#pragma unroll
    for (int cg = 0; cg < 4; ++cg)
#pragma unroll
        for (int i = 0; i < 16; ++i) acc[cg][i] = 0.f;

#pragma unroll
    for (int cg = 0; cg < 4; ++cg) {
        const int c = w * 4 + cg;
#pragma unroll
        for (int kl = 0; kl < 4; ++kl) {
            const uint32_t* up = uh + (size_t)((k0 + kl) * Cc + c) * 512 + lane * 4;
            uint4 q0 = *(const uint4*)up;
            uint4 q1 = *(const uint4*)(up + 256);
            const float w0 = agr[(kl * 64 + c) * 33 + m];
            const float w1 = agr[(kl * 64 + c) * 33 + 16 + m];
            acc[cg][0]  += w0 * bflo(q0.x);  acc[cg][1]  += w0 * bfhi(q0.x);
            acc[cg][2]  += w0 * bflo(q0.y);  acc[cg][3]  += w0 * bfhi(q0.y);
            acc[cg][4]  += w1 * bflo(q0.z);  acc[cg][5]  += w1 * bfhi(q0.z);
            acc[cg][6]  += w1 * bflo(q0.w);  acc[cg][7]  += w1 * bfhi(q0.w);
            acc[cg][8]  += w0 * bflo(q1.x);  acc[cg][9]  += w0 * bfhi(q1.x);
            acc[cg][10] += w0 * bflo(q1.y);  acc[cg][11] += w0 * bfhi(q1.y);
            acc[cg][12] += w1 * bflo(q1.z);  acc[cg][13] += w1 * bfhi(q1.z);
            acc[cg][14] += w1 * bflo(q1.w);  acc[cg][15] += w1 * bfhi(q1.w);
        }
    }

    // epilogue: pack + write partB (bf16)
    const int chunk = blockIdx.x;
#pragma unroll
    for (int cg = 0; cg < 4; ++cg) {
        const int c = w * 4 + cg;
        uint4 o0, o1;
        o0.x = pk2(acc[cg][0],  acc[cg][1]);  o0.y = pk2(acc[cg][2],  acc[cg][3]);
        o0.z = pk2(acc[cg][4],  acc[cg][5]);  o0.w = pk2(acc[cg][6],  acc[cg][7]);
        o1.x = pk2(acc[cg][8],  acc[cg][9]);  o1.y = pk2(acc[cg][10], acc[cg][11]);
        o1.z = pk2(acc[cg][12], acc[cg][13]); o1.w = pk2(acc[cg][14], acc[cg][15]);
        uint32_t* dst = partB + ((size_t)(c * 256 + chunk) * 64 + lane) * 8;
        *(uint4*)dst = o0;
        *(uint4*)(dst + 4) = o1;
    }
}

// Stage-1 reduce of 256 bf16 chunk-partials: block = (c, g of 8), sums 32 chunks.
__global__ __launch_bounds__(256) void k_red1(const uint32_t* __restrict__ partB,
                                              float* __restrict__ part2) {
    __shared__ float red[4 * 64 * 17];
    const int cb = blockIdx.x;          // c*8+g
    const int c = cb >> 3;
    const int g = cb & 7;
    const int tid = threadIdx.x;
    const int lane = tid & 63;
    const int ww = tid >> 6;

    float acc[16];
#pragma unroll
    for (int i = 0; i < 16; ++i) acc[i] = 0.f;
    for (int ch = g * 32 + ww * 8; ch < g * 32 + ww * 8 + 8; ++ch) {
        const uint32_t* p = partB + ((size_t)(c * 256 + ch) * 64 + lane) * 8;
        uint4 a = *(const uint4*)p;
        uint4 b = *(const uint4*)(p + 4);
        acc[0]  += bflo(a.x);  acc[1]  += bfhi(a.x);
        acc[2]  += bflo(a.y);  acc[3]  += bfhi(a.y);
        acc[4]  += bflo(a.z);  acc[5]  += bfhi(a.z);
        acc[6]  += bflo(a.w);  acc[7]  += bfhi(a.w);
        acc[8]  += bflo(b.x);  acc[9]  += bfhi(b.x);
        acc[10] += bflo(b.y);  acc[11] += bfhi(b.y);
        acc[12] += bflo(b.z);  acc[13] += bfhi(b.z);
        acc[14] += bflo(b.w);  acc[15] += bfhi(b.w);
    }
#pragma unroll
    for (int i = 0; i < 16; ++i) red[(ww * 64 + lane) * 17 + i] = acc[i];
    __syncthreads();

    if (tid < 64) {
        float a[16];
#pragma unroll
        for (int i = 0; i < 16; ++i)
            a[i] = red[tid * 17 + i] + red[(64 + tid) * 17 + i]
                 + red[(128 + tid) * 17 + i] + red[(192 + tid) * 17 + i];
        float* dst = part2 + ((size_t)cb * 64 + tid) * 16;
#pragma unroll
        for (int t = 0; t < 4; ++t) {
            f32x4 v = {a[t * 4 + 0], a[t * 4 + 1], a[t * 4 + 2], a[t * 4 + 3]};
            *(f32x4*)(dst + t * 4) = v;
        }
    }
}

// Stage-2: sum 8 fp32 partials + squash -> vfrag (+ out_v on FINAL).
template <bool FINAL>
__global__ __launch_bounds__(64) void k_red2(const float* __restrict__ part2,
                                             float* __restrict__ vfrag,
                                             float* __restrict__ out_v) {
    const int c = blockIdx.x;
    const int lane = threadIdx.x;
    const int m = lane & 15;
    const int q = lane >> 4;

    float a[16];
#pragma unroll
    for (int i = 0; i < 16; ++i) a[i] = 0.f;
    for (int g = 0; g < 8; ++g) {
        const float* p = part2 + ((size_t)(c * 8 + g) * 64 + lane) * 16;
#pragma unroll
        for (int t = 0; t < 4; ++t) {
            f32x4 v = *(const f32x4*)(p + t * 4);
            a[t * 4 + 0] += v.x; a[t * 4 + 1] += v.y;
            a[t * 4 + 2] += v.z; a[t * 4 + 3] += v.w;
        }
    }
    float sq0 = 0.f, sq1 = 0.f;
#pragma unroll
    for (int r = 0; r < 4; ++r) {
        sq0 += a[r] * a[r] + a[8 + r] * a[8 + r];
        sq1 += a[4 + r] * a[4 + r] + a[12 + r] * a[12 + r];
    }
    sq0 += __shfl_xor(sq0, 16); sq0 += __shfl_xor(sq0, 32);
    sq1 += __shfl_xor(sq1, 16); sq1 += __shfl_xor(sq1, 32);
    const float c0 = sq0 / ((1.f + sq0) * sqrtf(sq0 + 1e-8f));
    const float c1 = sq1 / ((1.f + sq1) * sqrtf(sq1 + 1e-8f));
#pragma unroll
    for (int r = 0; r < 4; ++r) {
        a[r] *= c0; a[8 + r] *= c0;
        a[4 + r] *= c1; a[12 + r] *= c1;
    }
    float* vp = vfrag + ((size_t)c * 64 + lane) * 16;
#pragma unroll
    for (int t = 0; t < 4; ++t) {
        f32x4 v = {a[t * 4 + 0], a[t * 4 + 1], a[t * 4 + 2], a[t * 4 + 3]};
        *(f32x4*)(vp + t * 4) = v;
    }
    if (FINAL) {
#pragma unroll
        for (int t = 0; t < 4; ++t)
#pragma unroll
            for (int r = 0; r < 4; ++r) {
                const int b = (t & 1) * 16 + m;
                const int o = (t >> 1) * 16 + q * 4 + r;
                out_v[((size_t)b * Cc + c) * Oo + o] = a[t * 4 + r];
            }
    }
}

extern "C" void kernel_launch(void* const* d_in, const int* in_sizes, int n_in,
                              void* d_out, int out_size, void* d_ws, size_t ws_size,
                              hipStream_t stream) {
    (void)in_sizes; (void)n_in; (void)out_size;
    const float* x = (const float*)d_in[0];
    const float* W = (const float*)d_in[1];
    float* out_v = (float*)d_out;                  // [B][C][O]
    float* out_c = out_v + Bb * Cc * Oo;           // [B][K][C]

    char* ws = (char*)d_ws;
    const size_t UH_BYTES = (size_t)Kk * Cc * 512 * 4;            // 128 MiB (bf16)
    const size_t XT_BYTES = (size_t)Kk * 512 * 4;                 // 2 MiB
    const size_t P0_BYTES = (size_t)64 * Cc * 64 * 16 * 4;        // 16 MiB
    const size_t PB_BYTES = (size_t)Cc * 256 * 64 * 8 * 4;        // 32 MiB
    const size_t P2_BYTES = (size_t)512 * 64 * 16 * 4;            // 2 MiB
    const size_t BB_BYTES = (size_t)Kk * Bb * Cc * 4;             // 8 MiB
    const size_t VF_BYTES = (size_t)Cc * 64 * 16 * 4;             // 256 KiB

    uint32_t* uh = (uint32_t*)ws;                      ws += UH_BYTES;
    uint32_t* xT = (uint32_t*)ws;                      ws += XT_BYTES;
    float* part0  = (float*)ws;                        ws += P0_BYTES;
    uint32_t* partB = (uint32_t*)ws;                   ws += PB_BYTES;
    float* part2  = (float*)ws;                        ws += P2_BYTES;
    float* bbuf   = (float*)ws;                        ws += BB_BYTES;
    float* vfrag  = (float*)ws;                        ws += VF_BYTES;
    const size_t NEED = UH_BYTES + XT_BYTES + P0_BYTES + PB_BYTES + P2_BYTES + BB_BYTES + VF_BYTES;
    if (ws_size < NEED) return;

    k_xT<<<Kk, 256, 0, stream>>>(x, xT);
    // u_hat + fused iter-0 s partials
    k_uhat<<<1024, 256, 0, stream>>>(xT, W, uh, part0);
    k_redA<<<Cc, 256, 0, stream>>>(part0, vfrag);            // v0
    // iter 1: agreement(v0) -> b1 -> softmax c1 -> s1 partials
    k_iter<false><<<256, 1024, 0, stream>>>(uh, vfrag, bbuf, partB, nullptr);
    k_red1<<<512, 256, 0, stream>>>(partB, part2);
    k_red2<false><<<Cc, 64, 0, stream>>>(part2, vfrag, nullptr);   // v1
    // iter 2: agreement(v1) -> b2 -> softmax c2 (out_c) -> s2 partials
    k_iter<true><<<256, 1024, 0, stream>>>(uh, vfrag, bbuf, partB, out_c);
    k_red1<<<512, 256, 0, stream>>>(partB, part2);
    k_red2<true><<<Cc, 64, 0, stream>>>(part2, vfrag, out_v);      // v2 = out_v
}